// Round 22
// baseline (99.999 us; speedup 1.0000x reference)
//
#include <hip/hip_runtime.h>

#define NN 50000
#define NE 1600000
#define D 64
#define NR 6
#define NSEG (NN * NR)          // 300000
#define SB 512
#define BFRAG_N (4 * 14 * 64 * 8)    // 28672
#define EPB 6400                // edges per pass-1 block
#define NBLK1 (NE / EPB)        // 250 (exact)
#define BUKSH 8                 // 256 segments per bucket
#define NBUK ((NSEG + 255) >> 8)     // 1172
#define NG (NBUK * NBLK1)       // 293000
#define SNB1 ((NG + SB - 1) / SB)    // 573
#define PREPB ((NN * D / 8 + 255) / 256)   // 1563 prep blocks
#define AGGW (NSEG / 16)        // 18750 agg waves

typedef __attribute__((ext_vector_type(8))) short short8;
typedef __attribute__((ext_vector_type(4))) float f32x4;

__device__ __forceinline__ unsigned short f2bf(float f) {
    unsigned int u = __float_as_uint(f);
    unsigned int r = (u + 0x7FFF + ((u >> 16) & 1)) >> 16;   // RNE
    return (unsigned short)r;
}
__device__ __forceinline__ float bflo(unsigned int w) { return __uint_as_float(w << 16); }
__device__ __forceinline__ float bfhi(unsigned int w) { return __uint_as_float(w & 0xFFFF0000u); }

// fused: blocks [0,NBLK1) = bucket histogram; rest = x->bf16 (xh) + Bfrag
__global__ __launch_bounds__(256) void prep_hist_k(const float* __restrict__ x,
                                                   const float* __restrict__ W,
                                                   const float* __restrict__ root,
                                                   const int* __restrict__ dsts,
                                                   const int* __restrict__ et,
                                                   int* __restrict__ ghist,
                                                   unsigned short* __restrict__ xh,
                                                   unsigned short* __restrict__ Bfrag) {
    __shared__ int lh[NBUK];
    int tid = threadIdx.x;
    if (blockIdx.x < NBLK1) {
        int blk = blockIdx.x;
        for (int i = tid; i < NBUK; i += 256) lh[i] = 0;
        __syncthreads();
        int base = blk * EPB;
#pragma unroll 5
        for (int i = 0; i < EPB / 256; ++i) {
            int e = base + i * 256 + tid;
            int seg = dsts[e] * NR + et[e];
            atomicAdd(&lh[seg >> BUKSH], 1);
        }
        __syncthreads();
        for (int i = tid; i < NBUK; i += 256) ghist[i * NBLK1 + blk] = lh[i];
    } else {
        int t = (blockIdx.x - NBLK1) * 256 + tid;
        if (t < NN * D / 8) {
            const float4* xp = (const float4*)(x + (size_t)t * 8);
            float4 va = xp[0], vb = xp[1];
            uint4 o;
            o.x = (unsigned int)f2bf(va.x) | ((unsigned int)f2bf(va.y) << 16);
            o.y = (unsigned int)f2bf(va.z) | ((unsigned int)f2bf(va.w) << 16);
            o.z = (unsigned int)f2bf(vb.x) | ((unsigned int)f2bf(vb.y) << 16);
            o.w = (unsigned int)f2bf(vb.z) | ((unsigned int)f2bf(vb.w) << 16);
            *(uint4*)(xh + (size_t)t * 8) = o;
        }
        if (t < BFRAG_N) {
            int j = t & 7;
            int lane = (t >> 3) & 63;
            int rest = t >> 9;
            int ks = rest % 14;
            int nt = rest / 14;
            int k = ks * 32 + ((lane >> 4) * 8) + j;
            int n = nt * 16 + (lane & 15);
            float v = (k < 384) ? W[(size_t)k * 64 + n] : root[(size_t)(k - 384) * 64 + n];
            Bfrag[t] = f2bf(v);
        }
    }
}

// ---- scan over ghist[NG] (bucket-major) -> exclusive goff[NG] ----
__global__ void scanA_k(const int* __restrict__ v, int* __restrict__ incl,
                        int* __restrict__ blocksum, int n) {
    __shared__ int s[SB];
    int t = threadIdx.x, i = blockIdx.x * SB + t;
    s[t] = (i < n) ? v[i] : 0;
    __syncthreads();
    for (int off = 1; off < SB; off <<= 1) {
        int u = (t >= off) ? s[t - off] : 0;
        __syncthreads();
        s[t] += u;
        __syncthreads();
    }
    if (i < n) incl[i] = s[t];
    if (t == SB - 1) blocksum[blockIdx.x] = s[t];
}

__global__ void scanB_k(const int* __restrict__ blocksum, int* __restrict__ blockoff, int nb) {
    __shared__ int s[1024];
    int t = threadIdx.x;
    s[t] = (t < nb) ? blocksum[t] : 0;
    __syncthreads();
    for (int off = 1; off < 1024; off <<= 1) {
        int u = (t >= off) ? s[t - off] : 0;
        __syncthreads();
        s[t] += u;
        __syncthreads();
    }
    if (t < nb) blockoff[t] = s[t];
}

__global__ void scanC2_k(const int* __restrict__ incl, const int* __restrict__ blockoff,
                         const int* __restrict__ v, int* __restrict__ excl, int n) {
    int i = blockIdx.x * blockDim.x + threadIdx.x;
    if (i >= n) return;
    int b = i / SB;
    int Ri = incl[i] + (b > 0 ? blockoff[b - 1] : 0);
    excl[i] = Ri - v[i];
}

// pass 1b: scatter edges into bucket-grouped kv = (src<<7, seg); LDS cursors
__global__ __launch_bounds__(256) void scatter1_k(const int* __restrict__ srcs,
                                                  const int* __restrict__ dsts,
                                                  const int* __restrict__ et,
                                                  const int* __restrict__ goff,
                                                  uint2* __restrict__ kv) {
    __shared__ int cur[NBUK];
    int tid = threadIdx.x, blk = blockIdx.x;
    for (int i = tid; i < NBUK; i += 256) cur[i] = goff[i * NBLK1 + blk];
    __syncthreads();
    int base = blk * EPB;
#pragma unroll 5
    for (int i = 0; i < EPB / 256; ++i) {
        int e = base + i * 256 + tid;
        int seg = dsts[e] * NR + et[e];
        int pos = atomicAdd(&cur[seg >> BUKSH], 1);
        kv[pos] = make_uint2((unsigned int)srcs[e] << 7, (unsigned int)seg);
    }
}

// pass 2: one block per 256-segment bucket; LDS histogram -> rowstart + pay
__global__ __launch_bounds__(256) void bucket2_k(const uint2* __restrict__ kv,
                                                 const int* __restrict__ goff,
                                                 int* __restrict__ rowstart,
                                                 int* __restrict__ pay) {
    __shared__ int h[256];
    __shared__ int part[256];
    int tid = threadIdx.x, b = blockIdx.x;
    int base = goff[b * NBLK1];
    int end  = (b + 1 < NBUK) ? goff[(b + 1) * NBLK1] : NE;
    h[tid] = 0;
    __syncthreads();
    for (int k = base + tid; k < end; k += 256)
        atomicAdd(&h[kv[k].y & 255], 1);
    __syncthreads();
    int c0 = h[tid];
    part[tid] = c0;
    __syncthreads();
    for (int off = 1; off < 256; off <<= 1) {
        int u = (tid >= off) ? part[tid - off] : 0;
        __syncthreads();
        part[tid] += u;
        __syncthreads();
    }
    int e0 = part[tid] - c0;             // exclusive within bucket
    __syncthreads();
    h[tid] = e0;
    int segb = b << BUKSH;
    if (segb + tid < NSEG) rowstart[segb + tid] = base + e0;
    if (b == 0 && tid == 0) rowstart[NSEG] = NE;
    __syncthreads();
    for (int k = base + tid; k < end; k += 256) {
        uint2 v = kv[k];
        int pos = base + atomicAdd(&h[v.y & 255], 1);
        pay[pos] = (int)v.x;
    }
}

// SIXTEEN segments per wave: lane group g=lane>>2 owns segment 16*wv+g;
// q=lane&3 owns channel half {16q..16q+15} (2x uint4 = 32B; 4 lanes = 128B row).
// Unmasked 4-edge main loop + masked <=3 tail (rounds 16-21 discipline).
__global__ __launch_bounds__(256) void agg14_k(const unsigned short* __restrict__ xh,
                                               const int* __restrict__ rowstart,
                                               const int* __restrict__ pay,
                                               unsigned short* __restrict__ Amain) {
    int wv = (blockIdx.x * blockDim.x + threadIdx.x) >> 6;
    if (wv >= AGGW) return;
    int lane = threadIdx.x & 63;
    int g = lane >> 2;
    int q = lane & 3;
    int seg = 16 * wv + g;
    int k0 = rowstart[seg], k1 = rowstart[seg + 1];
    const char* xb = (const char*)xh;
    unsigned int qo = (unsigned int)q << 5;                  // byte offset within row
    float acc[16];
#pragma unroll
    for (int c = 0; c < 16; ++c) acc[c] = 0.f;
    int len = k1 - k0;
    int k = k0;
    int k4 = k0 + (len & ~3);
    for (; k < k4; k += 4) {
        unsigned int pv[4];
#pragma unroll
        for (int j = 0; j < 4; ++j) pv[j] = (unsigned int)pay[k + j];
        uint4 uv[4], vv[4];
#pragma unroll
        for (int j = 0; j < 4; ++j) {
            uv[j] = *(const uint4*)(xb + pv[j] + qo);
            vv[j] = *(const uint4*)(xb + pv[j] + qo + 16);
        }
#pragma unroll
        for (int j = 0; j < 4; ++j) {
            acc[0]  += bflo(uv[j].x); acc[1]  += bfhi(uv[j].x);
            acc[2]  += bflo(uv[j].y); acc[3]  += bfhi(uv[j].y);
            acc[4]  += bflo(uv[j].z); acc[5]  += bfhi(uv[j].z);
            acc[6]  += bflo(uv[j].w); acc[7]  += bfhi(uv[j].w);
            acc[8]  += bflo(vv[j].x); acc[9]  += bfhi(vv[j].x);
            acc[10] += bflo(vv[j].y); acc[11] += bfhi(vv[j].y);
            acc[12] += bflo(vv[j].z); acc[13] += bfhi(vv[j].z);
            acc[14] += bflo(vv[j].w); acc[15] += bfhi(vv[j].w);
        }
    }
    if (k < k1) {                       // masked tail: 1..3 edges
        unsigned int pv[3];
        float mv[3];
#pragma unroll
        for (int j = 0; j < 3; ++j) {
            int kk = k + j;
            bool v = kk < k1;
            mv[j] = v ? 1.0f : 0.0f;
            pv[j] = (unsigned int)pay[v ? kk : k];
        }
#pragma unroll
        for (int j = 0; j < 3; ++j) {
            uint4 u = *(const uint4*)(xb + pv[j] + qo);
            uint4 v2 = *(const uint4*)(xb + pv[j] + qo + 16);
            acc[0]  += bflo(u.x) * mv[j];  acc[1]  += bfhi(u.x) * mv[j];
            acc[2]  += bflo(u.y) * mv[j];  acc[3]  += bfhi(u.y) * mv[j];
            acc[4]  += bflo(u.z) * mv[j];  acc[5]  += bfhi(u.z) * mv[j];
            acc[6]  += bflo(u.w) * mv[j];  acc[7]  += bfhi(u.w) * mv[j];
            acc[8]  += bflo(v2.x) * mv[j]; acc[9]  += bfhi(v2.x) * mv[j];
            acc[10] += bflo(v2.y) * mv[j]; acc[11] += bfhi(v2.y) * mv[j];
            acc[12] += bflo(v2.z) * mv[j]; acc[13] += bfhi(v2.z) * mv[j];
            acc[14] += bflo(v2.w) * mv[j]; acc[15] += bfhi(v2.w) * mv[j];
        }
    }
    float nrm = (len > 0) ? 1.0f / (float)len : 0.0f;
    uint4 o, p;
    o.x = (unsigned int)f2bf(acc[0] * nrm)  | ((unsigned int)f2bf(acc[1] * nrm) << 16);
    o.y = (unsigned int)f2bf(acc[2] * nrm)  | ((unsigned int)f2bf(acc[3] * nrm) << 16);
    o.z = (unsigned int)f2bf(acc[4] * nrm)  | ((unsigned int)f2bf(acc[5] * nrm) << 16);
    o.w = (unsigned int)f2bf(acc[6] * nrm)  | ((unsigned int)f2bf(acc[7] * nrm) << 16);
    p.x = (unsigned int)f2bf(acc[8] * nrm)  | ((unsigned int)f2bf(acc[9] * nrm) << 16);
    p.y = (unsigned int)f2bf(acc[10] * nrm) | ((unsigned int)f2bf(acc[11] * nrm) << 16);
    p.z = (unsigned int)f2bf(acc[12] * nrm) | ((unsigned int)f2bf(acc[13] * nrm) << 16);
    p.w = (unsigned int)f2bf(acc[14] * nrm) | ((unsigned int)f2bf(acc[15] * nrm) << 16);
    char* ob = (char*)Amain + (size_t)seg * 128 + qo;
    *(uint4*)ob = o;
    *(uint4*)(ob + 16) = p;
}

// MFMA GEMM: K slots 0-383 from Amain, 384-447 (root term) from xh. (round-18 exact)
__global__ __launch_bounds__(256) void mix4_k(const unsigned short* __restrict__ Amain,
                                              const unsigned short* __restrict__ xh,
                                              const unsigned short* __restrict__ Bfrag,
                                              const float* __restrict__ bias,
                                              float* __restrict__ out) {
    int t = threadIdx.x;
    int lane = t & 63;
    int w = t >> 6;
    int rowb = blockIdx.x * 64 + w * 16;
    int arow = rowb + (lane & 15);
    if (arow >= NN) arow = NN - 1;
    int ko = (lane >> 4) * 8;
    const unsigned short* ap = Amain + (size_t)arow * 384 + ko;
    const unsigned short* xp = xh + (size_t)arow * 64 + ko;
    const short8* bp = (const short8*)Bfrag + lane;
    f32x4 acc0 = {0.f, 0.f, 0.f, 0.f};
    f32x4 acc1 = acc0, acc2 = acc0, acc3 = acc0;
#pragma unroll
    for (int ks = 0; ks < 14; ++ks) {
        short8 a = (ks < 12) ? *(const short8*)(ap + ks * 32)
                             : *(const short8*)(xp + (ks - 12) * 32);
        short8 b0 = bp[(0 * 14 + ks) * 64];
        short8 b1 = bp[(1 * 14 + ks) * 64];
        short8 b2 = bp[(2 * 14 + ks) * 64];
        short8 b3 = bp[(3 * 14 + ks) * 64];
        acc0 = __builtin_amdgcn_mfma_f32_16x16x32_bf16(a, b0, acc0, 0, 0, 0);
        acc1 = __builtin_amdgcn_mfma_f32_16x16x32_bf16(a, b1, acc1, 0, 0, 0);
        acc2 = __builtin_amdgcn_mfma_f32_16x16x32_bf16(a, b2, acc2, 0, 0, 0);
        acc3 = __builtin_amdgcn_mfma_f32_16x16x32_bf16(a, b3, acc3, 0, 0, 0);
    }
    int col = lane & 15;
    int rout = rowb + (lane >> 4) * 4;
    float bv0 = bias[0 * 16 + col];
    float bv1 = bias[1 * 16 + col];
    float bv2 = bias[2 * 16 + col];
    float bv3 = bias[3 * 16 + col];
#pragma unroll
    for (int j = 0; j < 4; ++j) {
        int rr = rout + j;
        if (rr < NN) {
            float* op = out + (size_t)rr * 64;
            op[0 * 16 + col] = acc0[j] + bv0;
            op[1 * 16 + col] = acc1[j] + bv1;
            op[2 * 16 + col] = acc2[j] + bv2;
            op[3 * 16 + col] = acc3[j] + bv3;
        }
    }
}

// ---------- fallback path (small ws) ----------
__global__ void zero_i32_k(int* __restrict__ p, int n) {
    int i = blockIdx.x * blockDim.x + threadIdx.x;
    if (i < n) p[i] = 0;
}

__global__ void count_edges_k(const int* __restrict__ dst, const int* __restrict__ et,
                              int* __restrict__ cnt) {
    int e = blockIdx.x * blockDim.x + threadIdx.x;
    if (e < NE) atomicAdd(&cnt[dst[e] * NR + et[e]], 1);
}

__global__ void make_norm_k(const int* __restrict__ cnt, float* __restrict__ norm, int n) {
    int i = blockIdx.x * blockDim.x + threadIdx.x;
    if (i < n) {
        int c = cnt[i];
        norm[i] = (c > 0) ? 1.0f / (float)c : 0.0f;
    }
}

__global__ void init_out_k(const float* __restrict__ x, const float* __restrict__ root,
                           const float* __restrict__ bias, float* __restrict__ out) {
    int t = blockIdx.x * blockDim.x + threadIdx.x;
    int n = t >> 6;
    int o = t & 63;
    if (n >= NN) return;
    const float* xrow = x + n * D;
    float acc = bias[o];
#pragma unroll
    for (int d = 0; d < D; ++d) acc = fmaf(xrow[d], root[d * D + o], acc);
    out[t] = acc;
}

__global__ void scatter_mv_k(const int* __restrict__ srcs, const int* __restrict__ dsts,
                             const int* __restrict__ et, const float* __restrict__ x,
                             const float* __restrict__ W, const float* __restrict__ norm,
                             float* __restrict__ out) {
    int t = blockIdx.x * blockDim.x + threadIdx.x;
    int e = t >> 6;
    int o = t & 63;
    if (e >= NE) return;
    int s = srcs[e];
    int d2 = dsts[e];
    int r = et[e];
    float nrm = norm[d2 * NR + r];
    const float* xrow = x + s * D;
    const float* Wr = W + r * D * D + o;
    float acc = 0.0f;
#pragma unroll
    for (int d = 0; d < D; ++d) acc = fmaf(xrow[d], Wr[d * D], acc);
    atomicAdd(&out[d2 * D + o], acc * nrm);
}

extern "C" void kernel_launch(void* const* d_in, const int* in_sizes, int n_in,
                              void* d_out, int out_size, void* d_ws, size_t ws_size,
                              hipStream_t stream) {
    const float* x    = (const float*)d_in[0];
    const float* W    = (const float*)d_in[1];
    const float* root = (const float*)d_in[2];
    const float* bias = (const float*)d_in[3];
    const int*   ei   = (const int*)d_in[4];
    const int*   et   = (const int*)d_in[5];
    float* out = (float*)d_out;
    const int* srcs = ei;
    const int* dsts = ei + NE;

    // workspace layout (~70 MB)
    char* ws = (char*)d_ws;
    size_t off = 0;
    int*   rowstart = (int*)(ws + off); off += (size_t)(NSEG + 1) * 4;
    int*   pay      = (int*)(ws + off); off += (size_t)NE * 4;
    off = (off + 255) & ~(size_t)255;
    uint2* kv       = (uint2*)(ws + off); off += (size_t)NE * 8;
    int*   ghist    = (int*)(ws + off); off += (size_t)NG * 4;
    int*   incl     = (int*)(ws + off); off += (size_t)NG * 4;
    int*   goff     = (int*)(ws + off); off += (size_t)NG * 4;
    int*   blocksum = (int*)(ws + off); off += (size_t)SNB1 * 4;
    int*   blockoff = (int*)(ws + off); off += (size_t)SNB1 * 4;
    off = (off + 255) & ~(size_t)255;
    unsigned short* Bfrag = (unsigned short*)(ws + off); off += (size_t)BFRAG_N * 2;
    off = (off + 255) & ~(size_t)255;
    unsigned short* xh = (unsigned short*)(ws + off); off += (size_t)NN * D * 2;
    off = (off + 255) & ~(size_t)255;
    unsigned short* Amain = (unsigned short*)(ws + off); off += (size_t)NN * 384 * 2;
    bool big = ws_size >= off;

    if (big) {
        prep_hist_k<<<NBLK1 + PREPB, 256, 0, stream>>>(x, W, root, dsts, et, ghist, xh, Bfrag);
        scanA_k<<<SNB1, SB, 0, stream>>>(ghist, incl, blocksum, NG);
        scanB_k<<<1, 1024, 0, stream>>>(blocksum, blockoff, SNB1);
        scanC2_k<<<(NG + 255) / 256, 256, 0, stream>>>(incl, blockoff, ghist, goff, NG);
        scatter1_k<<<NBLK1, 256, 0, stream>>>(srcs, dsts, et, goff, kv);
        bucket2_k<<<NBUK, 256, 0, stream>>>(kv, goff, rowstart, pay);
        agg14_k<<<((size_t)AGGW * 64 + 255) / 256, 256, 0, stream>>>(xh, rowstart, pay, Amain);
        mix4_k<<<(NN + 63) / 64, 256, 0, stream>>>(Amain, xh, Bfrag, bias, out);
    } else {
        int* cnt2  = (int*)(ws);
        float* norm = (float*)(ws + (size_t)NSEG * 4);
        zero_i32_k<<<(NSEG + 255) / 256, 256, 0, stream>>>(cnt2, NSEG);
        count_edges_k<<<(NE + 255) / 256, 256, 0, stream>>>(dsts, et, cnt2);
        make_norm_k<<<(NSEG + 255) / 256, 256, 0, stream>>>(cnt2, norm, NSEG);
        init_out_k<<<((size_t)NN * 64 + 255) / 256, 256, 0, stream>>>(x, root, bias, out);
        scatter_mv_k<<<((size_t)NE * 64 + 255) / 256, 256, 0, stream>>>(srcs, dsts, et, x, W, norm, out);
    }
}

// Round 23
// 95.357 us; speedup vs baseline: 1.0487x; 1.0487x over previous
//
#include <hip/hip_runtime.h>

#define NN 50000
#define NE 1600000
#define D 64
#define NR 6
#define NSEG (NN * NR)          // 300000
#define SB 512
#define BFRAG_N (4 * 14 * 64 * 8)    // 28672
#define EPB 6400                // edges per pass-1 block
#define NBLK1 (NE / EPB)        // 250 (exact)
#define BUKSH 9                 // 512 segments per bucket
#define NBUK ((NSEG + 511) >> 9)     // 586
#define NG (NBUK * NBLK1)       // 146500
#define SNB1 ((NG + SB - 1) / SB)    // 287
#define PREPB ((NN * D / 8 + 255) / 256)   // 1563 prep blocks

typedef __attribute__((ext_vector_type(8))) short short8;
typedef __attribute__((ext_vector_type(4))) float f32x4;

__device__ __forceinline__ unsigned short f2bf(float f) {
    unsigned int u = __float_as_uint(f);
    unsigned int r = (u + 0x7FFF + ((u >> 16) & 1)) >> 16;   // RNE
    return (unsigned short)r;
}

// fused: blocks [0,NBLK1) = bucket histogram; rest = x->bf16 (xh) + Bfrag
__global__ __launch_bounds__(256) void prep_hist_k(const float* __restrict__ x,
                                                   const float* __restrict__ W,
                                                   const float* __restrict__ root,
                                                   const int* __restrict__ dsts,
                                                   const int* __restrict__ et,
                                                   int* __restrict__ ghist,
                                                   unsigned short* __restrict__ xh,
                                                   unsigned short* __restrict__ Bfrag) {
    __shared__ int lh[NBUK];
    int tid = threadIdx.x;
    if (blockIdx.x < NBLK1) {
        int blk = blockIdx.x;
        for (int i = tid; i < NBUK; i += 256) lh[i] = 0;
        __syncthreads();
        int base = blk * EPB;
#pragma unroll 5
        for (int i = 0; i < EPB / 256; ++i) {
            int e = base + i * 256 + tid;
            int seg = dsts[e] * NR + et[e];
            atomicAdd(&lh[seg >> BUKSH], 1);
        }
        __syncthreads();
        for (int i = tid; i < NBUK; i += 256) ghist[i * NBLK1 + blk] = lh[i];
    } else {
        int t = (blockIdx.x - NBLK1) * 256 + tid;
        if (t < NN * D / 8) {
            const float4* xp = (const float4*)(x + (size_t)t * 8);
            float4 va = xp[0], vb = xp[1];
            uint4 o;
            o.x = (unsigned int)f2bf(va.x) | ((unsigned int)f2bf(va.y) << 16);
            o.y = (unsigned int)f2bf(va.z) | ((unsigned int)f2bf(va.w) << 16);
            o.z = (unsigned int)f2bf(vb.x) | ((unsigned int)f2bf(vb.y) << 16);
            o.w = (unsigned int)f2bf(vb.z) | ((unsigned int)f2bf(vb.w) << 16);
            *(uint4*)(xh + (size_t)t * 8) = o;
        }
        if (t < BFRAG_N) {
            int j = t & 7;
            int lane = (t >> 3) & 63;
            int rest = t >> 9;
            int ks = rest % 14;
            int nt = rest / 14;
            int k = ks * 32 + ((lane >> 4) * 8) + j;
            int n = nt * 16 + (lane & 15);
            float v = (k < 384) ? W[(size_t)k * 64 + n] : root[(size_t)(k - 384) * 64 + n];
            Bfrag[t] = f2bf(v);
        }
    }
}

// ---- scan over ghist[NG] (bucket-major) -> exclusive goff[NG] ----
__global__ void scanA_k(const int* __restrict__ v, int* __restrict__ incl,
                        int* __restrict__ blocksum, int n) {
    __shared__ int s[SB];
    int t = threadIdx.x, i = blockIdx.x * SB + t;
    s[t] = (i < n) ? v[i] : 0;
    __syncthreads();
    for (int off = 1; off < SB; off <<= 1) {
        int u = (t >= off) ? s[t - off] : 0;
        __syncthreads();
        s[t] += u;
        __syncthreads();
    }
    if (i < n) incl[i] = s[t];
    if (t == SB - 1) blocksum[blockIdx.x] = s[t];
}

__global__ void scanB_k(const int* __restrict__ blocksum, int* __restrict__ blockoff, int nb) {
    __shared__ int s[1024];
    int t = threadIdx.x;
    s[t] = (t < nb) ? blocksum[t] : 0;
    __syncthreads();
    for (int off = 1; off < 1024; off <<= 1) {
        int u = (t >= off) ? s[t - off] : 0;
        __syncthreads();
        s[t] += u;
        __syncthreads();
    }
    if (t < nb) blockoff[t] = s[t];
}

__global__ void scanC2_k(const int* __restrict__ incl, const int* __restrict__ blockoff,
                         const int* __restrict__ v, int* __restrict__ excl, int n) {
    int i = blockIdx.x * blockDim.x + threadIdx.x;
    if (i >= n) return;
    int b = i / SB;
    int Ri = incl[i] + (b > 0 ? blockoff[b - 1] : 0);
    excl[i] = Ri - v[i];
}

// pass 1b: scatter edges into bucket-grouped kv = (src<<9)|(seg&511); LDS cursors
__global__ __launch_bounds__(256) void scatter1_k(const int* __restrict__ srcs,
                                                  const int* __restrict__ dsts,
                                                  const int* __restrict__ et,
                                                  const int* __restrict__ goff,
                                                  unsigned int* __restrict__ kv) {
    __shared__ int cur[NBUK];
    int tid = threadIdx.x, blk = blockIdx.x;
    for (int i = tid; i < NBUK; i += 256) cur[i] = goff[i * NBLK1 + blk];
    __syncthreads();
    int base = blk * EPB;
#pragma unroll 5
    for (int i = 0; i < EPB / 256; ++i) {
        int e = base + i * 256 + tid;
        int seg = dsts[e] * NR + et[e];
        int pos = atomicAdd(&cur[seg >> BUKSH], 1);
        kv[pos] = ((unsigned int)srcs[e] << BUKSH) | ((unsigned int)seg & 511u);
    }
}

// pass 2: one block per 512-segment bucket; LDS histogram -> rowstart + pay (ushort src)
__global__ __launch_bounds__(256) void bucket2_k(const unsigned int* __restrict__ kv,
                                                 const int* __restrict__ goff,
                                                 int* __restrict__ rowstart,
                                                 unsigned short* __restrict__ pay) {
    __shared__ int h[512];
    __shared__ int part[256];
    int tid = threadIdx.x, b = blockIdx.x;
    int base = goff[b * NBLK1];
    int end  = (b + 1 < NBUK) ? goff[(b + 1) * NBLK1] : NE;
    for (int i = tid; i < 512; i += 256) h[i] = 0;
    __syncthreads();
    for (int k = base + tid; k < end; k += 256)
        atomicAdd(&h[kv[k] & 511u], 1);
    __syncthreads();
    int c0 = h[2 * tid], c1 = h[2 * tid + 1];
    part[tid] = c0 + c1;
    __syncthreads();
    for (int off = 1; off < 256; off <<= 1) {
        int u = (tid >= off) ? part[tid - off] : 0;
        __syncthreads();
        part[tid] += u;
        __syncthreads();
    }
    int pbase = (tid > 0) ? part[tid - 1] : 0;   // exclusive across thread groups
    __syncthreads();
    int e0 = pbase, e1 = pbase + c0;
    h[2 * tid] = e0; h[2 * tid + 1] = e1;
    int segb = b << BUKSH;
    if (segb + 2 * tid     < NSEG) rowstart[segb + 2 * tid]     = base + e0;
    if (segb + 2 * tid + 1 < NSEG) rowstart[segb + 2 * tid + 1] = base + e1;
    if (b == 0 && tid == 0) rowstart[NSEG] = NE;
    __syncthreads();
    for (int k = base + tid; k < end; k += 256) {
        unsigned int v = kv[k];
        int pos = base + atomicAdd(&h[v & 511u], 1);
        pay[pos] = (unsigned short)(v >> BUKSH);
    }
}

// EIGHT segments per wave: lane group g=lane>>3 owns segment 8*wv+g;
// q=lane&7 owns channel octet {8q..8q+7} (uint4 = 16B gather; 8 lanes = 128B row).
// Unmasked 4-edge main loop + masked <=3 tail (round-16..21 discipline).
__global__ __launch_bounds__(256) void agg13_k(const unsigned short* __restrict__ xh,
                                               const int* __restrict__ rowstart,
                                               const unsigned short* __restrict__ pay,
                                               unsigned short* __restrict__ Amain) {
    int wv = (blockIdx.x * blockDim.x + threadIdx.x) >> 6;   // 0..37499 (grid exact)
    int lane = threadIdx.x & 63;
    int g = lane >> 3;
    int q = lane & 7;
    int seg = 8 * wv + g;
    int k0 = rowstart[seg], k1 = rowstart[seg + 1];
    const char* xb = (const char*)xh;
    unsigned int qo = (unsigned int)q << 4;                  // byte offset within row
    float a0 = 0.f, a1 = 0.f, a2 = 0.f, a3 = 0.f;
    float a4 = 0.f, a5 = 0.f, a6 = 0.f, a7 = 0.f;
    int len = k1 - k0;
    int k = k0;
    int k4 = k0 + (len & ~3);
    for (; k < k4; k += 4) {
        unsigned int pv[4];
#pragma unroll
        for (int j = 0; j < 4; ++j) pv[j] = (unsigned int)pay[k + j] << 7;
        uint4 uv[4];
#pragma unroll
        for (int j = 0; j < 4; ++j)
            uv[j] = *(const uint4*)(xb + pv[j] + qo);
#pragma unroll
        for (int j = 0; j < 4; ++j) {
            a0 += __uint_as_float(uv[j].x << 16);
            a1 += __uint_as_float(uv[j].x & 0xFFFF0000u);
            a2 += __uint_as_float(uv[j].y << 16);
            a3 += __uint_as_float(uv[j].y & 0xFFFF0000u);
            a4 += __uint_as_float(uv[j].z << 16);
            a5 += __uint_as_float(uv[j].z & 0xFFFF0000u);
            a6 += __uint_as_float(uv[j].w << 16);
            a7 += __uint_as_float(uv[j].w & 0xFFFF0000u);
        }
    }
    if (k < k1) {                       // masked tail: 1..3 edges
        unsigned int pv[3];
        float mv[3];
#pragma unroll
        for (int j = 0; j < 3; ++j) {
            int kk = k + j;
            bool v = kk < k1;
            mv[j] = v ? 1.0f : 0.0f;
            pv[j] = (unsigned int)pay[v ? kk : k] << 7;
        }
#pragma unroll
        for (int j = 0; j < 3; ++j) {
            uint4 u = *(const uint4*)(xb + pv[j] + qo);
            a0 += __uint_as_float(u.x << 16) * mv[j];
            a1 += __uint_as_float(u.x & 0xFFFF0000u) * mv[j];
            a2 += __uint_as_float(u.y << 16) * mv[j];
            a3 += __uint_as_float(u.y & 0xFFFF0000u) * mv[j];
            a4 += __uint_as_float(u.z << 16) * mv[j];
            a5 += __uint_as_float(u.z & 0xFFFF0000u) * mv[j];
            a6 += __uint_as_float(u.w << 16) * mv[j];
            a7 += __uint_as_float(u.w & 0xFFFF0000u) * mv[j];
        }
    }
    float nrm = (len > 0) ? 1.0f / (float)len : 0.0f;
    uint4 o;
    o.x = (unsigned int)f2bf(a0 * nrm) | ((unsigned int)f2bf(a1 * nrm) << 16);
    o.y = (unsigned int)f2bf(a2 * nrm) | ((unsigned int)f2bf(a3 * nrm) << 16);
    o.z = (unsigned int)f2bf(a4 * nrm) | ((unsigned int)f2bf(a5 * nrm) << 16);
    o.w = (unsigned int)f2bf(a6 * nrm) | ((unsigned int)f2bf(a7 * nrm) << 16);
    *(uint4*)((char*)Amain + (size_t)seg * 128 + qo) = o;
}

// MFMA GEMM: K slots 0-383 from Amain, 384-447 (root term) from xh. (round-18 exact)
__global__ __launch_bounds__(256) void mix4_k(const unsigned short* __restrict__ Amain,
                                              const unsigned short* __restrict__ xh,
                                              const unsigned short* __restrict__ Bfrag,
                                              const float* __restrict__ bias,
                                              float* __restrict__ out) {
    int t = threadIdx.x;
    int lane = t & 63;
    int w = t >> 6;
    int rowb = blockIdx.x * 64 + w * 16;
    int arow = rowb + (lane & 15);
    if (arow >= NN) arow = NN - 1;
    int ko = (lane >> 4) * 8;
    const unsigned short* ap = Amain + (size_t)arow * 384 + ko;
    const unsigned short* xp = xh + (size_t)arow * 64 + ko;
    const short8* bp = (const short8*)Bfrag + lane;
    f32x4 acc0 = {0.f, 0.f, 0.f, 0.f};
    f32x4 acc1 = acc0, acc2 = acc0, acc3 = acc0;
#pragma unroll
    for (int ks = 0; ks < 14; ++ks) {
        short8 a = (ks < 12) ? *(const short8*)(ap + ks * 32)
                             : *(const short8*)(xp + (ks - 12) * 32);
        short8 b0 = bp[(0 * 14 + ks) * 64];
        short8 b1 = bp[(1 * 14 + ks) * 64];
        short8 b2 = bp[(2 * 14 + ks) * 64];
        short8 b3 = bp[(3 * 14 + ks) * 64];
        acc0 = __builtin_amdgcn_mfma_f32_16x16x32_bf16(a, b0, acc0, 0, 0, 0);
        acc1 = __builtin_amdgcn_mfma_f32_16x16x32_bf16(a, b1, acc1, 0, 0, 0);
        acc2 = __builtin_amdgcn_mfma_f32_16x16x32_bf16(a, b2, acc2, 0, 0, 0);
        acc3 = __builtin_amdgcn_mfma_f32_16x16x32_bf16(a, b3, acc3, 0, 0, 0);
    }
    int col = lane & 15;
    int rout = rowb + (lane >> 4) * 4;
    float bv0 = bias[0 * 16 + col];
    float bv1 = bias[1 * 16 + col];
    float bv2 = bias[2 * 16 + col];
    float bv3 = bias[3 * 16 + col];
#pragma unroll
    for (int j = 0; j < 4; ++j) {
        int rr = rout + j;
        if (rr < NN) {
            float* op = out + (size_t)rr * 64;
            op[0 * 16 + col] = acc0[j] + bv0;
            op[1 * 16 + col] = acc1[j] + bv1;
            op[2 * 16 + col] = acc2[j] + bv2;
            op[3 * 16 + col] = acc3[j] + bv3;
        }
    }
}

// ---------- fallback path (small ws) ----------
__global__ void zero_i32_k(int* __restrict__ p, int n) {
    int i = blockIdx.x * blockDim.x + threadIdx.x;
    if (i < n) p[i] = 0;
}

__global__ void count_edges_k(const int* __restrict__ dst, const int* __restrict__ et,
                              int* __restrict__ cnt) {
    int e = blockIdx.x * blockDim.x + threadIdx.x;
    if (e < NE) atomicAdd(&cnt[dst[e] * NR + et[e]], 1);
}

__global__ void make_norm_k(const int* __restrict__ cnt, float* __restrict__ norm, int n) {
    int i = blockIdx.x * blockDim.x + threadIdx.x;
    if (i < n) {
        int c = cnt[i];
        norm[i] = (c > 0) ? 1.0f / (float)c : 0.0f;
    }
}

__global__ void init_out_k(const float* __restrict__ x, const float* __restrict__ root,
                           const float* __restrict__ bias, float* __restrict__ out) {
    int t = blockIdx.x * blockDim.x + threadIdx.x;
    int n = t >> 6;
    int o = t & 63;
    if (n >= NN) return;
    const float* xrow = x + n * D;
    float acc = bias[o];
#pragma unroll
    for (int d = 0; d < D; ++d) acc = fmaf(xrow[d], root[d * D + o], acc);
    out[t] = acc;
}

__global__ void scatter_mv_k(const int* __restrict__ srcs, const int* __restrict__ dsts,
                             const int* __restrict__ et, const float* __restrict__ x,
                             const float* __restrict__ W, const float* __restrict__ norm,
                             float* __restrict__ out) {
    int t = blockIdx.x * blockDim.x + threadIdx.x;
    int e = t >> 6;
    int o = t & 63;
    if (e >= NE) return;
    int s = srcs[e];
    int d2 = dsts[e];
    int r = et[e];
    float nrm = norm[d2 * NR + r];
    const float* xrow = x + s * D;
    const float* Wr = W + r * D * D + o;
    float acc = 0.0f;
#pragma unroll
    for (int d = 0; d < D; ++d) acc = fmaf(xrow[d], Wr[d * D], acc);
    atomicAdd(&out[d2 * D + o], acc * nrm);
}

extern "C" void kernel_launch(void* const* d_in, const int* in_sizes, int n_in,
                              void* d_out, int out_size, void* d_ws, size_t ws_size,
                              hipStream_t stream) {
    const float* x    = (const float*)d_in[0];
    const float* W    = (const float*)d_in[1];
    const float* root = (const float*)d_in[2];
    const float* bias = (const float*)d_in[3];
    const int*   ei   = (const int*)d_in[4];
    const int*   et   = (const int*)d_in[5];
    float* out = (float*)d_out;
    const int* srcs = ei;
    const int* dsts = ei + NE;

    // workspace layout (~58 MB)
    char* ws = (char*)d_ws;
    size_t off = 0;
    int*   rowstart = (int*)(ws + off); off += (size_t)(NSEG + 1) * 4;
    off = (off + 255) & ~(size_t)255;
    unsigned short* pay = (unsigned short*)(ws + off); off += (size_t)NE * 2;
    off = (off + 255) & ~(size_t)255;
    unsigned int* kv = (unsigned int*)(ws + off); off += (size_t)NE * 4;
    int*   ghist    = (int*)(ws + off); off += (size_t)NG * 4;
    int*   incl     = (int*)(ws + off); off += (size_t)NG * 4;
    int*   goff     = (int*)(ws + off); off += (size_t)NG * 4;
    int*   blocksum = (int*)(ws + off); off += (size_t)SNB1 * 4;
    int*   blockoff = (int*)(ws + off); off += (size_t)SNB1 * 4;
    off = (off + 255) & ~(size_t)255;
    unsigned short* Bfrag = (unsigned short*)(ws + off); off += (size_t)BFRAG_N * 2;
    off = (off + 255) & ~(size_t)255;
    unsigned short* xh = (unsigned short*)(ws + off); off += (size_t)NN * D * 2;
    off = (off + 255) & ~(size_t)255;
    unsigned short* Amain = (unsigned short*)(ws + off); off += (size_t)NN * 384 * 2;
    bool big = ws_size >= off;

    if (big) {
        prep_hist_k<<<NBLK1 + PREPB, 256, 0, stream>>>(x, W, root, dsts, et, ghist, xh, Bfrag);
        scanA_k<<<SNB1, SB, 0, stream>>>(ghist, incl, blocksum, NG);
        scanB_k<<<1, 1024, 0, stream>>>(blocksum, blockoff, SNB1);
        scanC2_k<<<(NG + 255) / 256, 256, 0, stream>>>(incl, blockoff, ghist, goff, NG);
        scatter1_k<<<NBLK1, 256, 0, stream>>>(srcs, dsts, et, goff, kv);
        bucket2_k<<<NBUK, 256, 0, stream>>>(kv, goff, rowstart, pay);
        int aggwaves = NSEG / 8;                      // 37500
        agg13_k<<<((size_t)aggwaves * 64 + 255) / 256, 256, 0, stream>>>(xh, rowstart, pay, Amain);
        mix4_k<<<(NN + 63) / 64, 256, 0, stream>>>(Amain, xh, Bfrag, bias, out);
    } else {
        int* cnt2  = (int*)(ws);
        float* norm = (float*)(ws + (size_t)NSEG * 4);
        zero_i32_k<<<(NSEG + 255) / 256, 256, 0, stream>>>(cnt2, NSEG);
        count_edges_k<<<(NE + 255) / 256, 256, 0, stream>>>(dsts, et, cnt2);
        make_norm_k<<<(NSEG + 255) / 256, 256, 0, stream>>>(cnt2, norm, NSEG);
        init_out_k<<<((size_t)NN * 64 + 255) / 256, 256, 0, stream>>>(x, root, bias, out);
        scatter_mv_k<<<((size_t)NE * 64 + 255) / 256, 256, 0, stream>>>(srcs, dsts, et, x, W, norm, out);
    }
}

// Round 24
// 94.818 us; speedup vs baseline: 1.0546x; 1.0057x over previous
//
#include <hip/hip_runtime.h>

#define NN 50000
#define NE 1600000
#define D 64
#define NR 6
#define NSEG (NN * NR)          // 300000
#define SB 512
#define BFRAG_N (4 * 14 * 64 * 8)    // 28672
#define EPB 6400                // edges per pass-1 block
#define NBLK1 (NE / EPB)        // 250 (exact)
#define BUKSH 9                 // 512 segments per bucket
#define NBUK ((NSEG + 511) >> 9)     // 586
#define NG (NBUK * NBLK1)       // 146500
#define SNB1 ((NG + SB - 1) / SB)    // 287
#define PREPB ((NN * D / 8 + 255) / 256)   // 1563 prep blocks
#define KVL_CAP 4096            // bucket2 LDS kv capacity (avg bucket ~2730)

typedef __attribute__((ext_vector_type(8))) short short8;
typedef __attribute__((ext_vector_type(4))) float f32x4;

__device__ __forceinline__ unsigned short f2bf(float f) {
    unsigned int u = __float_as_uint(f);
    unsigned int r = (u + 0x7FFF + ((u >> 16) & 1)) >> 16;   // RNE
    return (unsigned short)r;
}

// exclusive offset into the bucket-major ghist matrix, from scan outputs
__device__ __forceinline__ int excl_at(const int* __restrict__ incl,
                                       const int* __restrict__ blockoff,
                                       const int* __restrict__ ghist, int m) {
    int bo = (m >= SB) ? blockoff[m / SB - 1] : 0;
    return incl[m] + bo - ghist[m];
}

// fused: blocks [0,NBLK1) = bucket histogram; rest = x->bf16 (xh) + Bfrag
__global__ __launch_bounds__(256) void prep_hist_k(const float* __restrict__ x,
                                                   const float* __restrict__ W,
                                                   const float* __restrict__ root,
                                                   const int* __restrict__ dsts,
                                                   const int* __restrict__ et,
                                                   int* __restrict__ ghist,
                                                   unsigned short* __restrict__ xh,
                                                   unsigned short* __restrict__ Bfrag) {
    __shared__ int lh[NBUK];
    int tid = threadIdx.x;
    if (blockIdx.x < NBLK1) {
        int blk = blockIdx.x;
        for (int i = tid; i < NBUK; i += 256) lh[i] = 0;
        __syncthreads();
        int base = blk * EPB;
#pragma unroll 5
        for (int i = 0; i < EPB / 256; ++i) {
            int e = base + i * 256 + tid;
            int seg = dsts[e] * NR + et[e];
            atomicAdd(&lh[seg >> BUKSH], 1);
        }
        __syncthreads();
        for (int i = tid; i < NBUK; i += 256) ghist[i * NBLK1 + blk] = lh[i];
    } else {
        int t = (blockIdx.x - NBLK1) * 256 + tid;
        if (t < NN * D / 8) {
            const float4* xp = (const float4*)(x + (size_t)t * 8);
            float4 va = xp[0], vb = xp[1];
            uint4 o;
            o.x = (unsigned int)f2bf(va.x) | ((unsigned int)f2bf(va.y) << 16);
            o.y = (unsigned int)f2bf(va.z) | ((unsigned int)f2bf(va.w) << 16);
            o.z = (unsigned int)f2bf(vb.x) | ((unsigned int)f2bf(vb.y) << 16);
            o.w = (unsigned int)f2bf(vb.z) | ((unsigned int)f2bf(vb.w) << 16);
            *(uint4*)(xh + (size_t)t * 8) = o;
        }
        if (t < BFRAG_N) {
            int j = t & 7;
            int lane = (t >> 3) & 63;
            int rest = t >> 9;
            int ks = rest % 14;
            int nt = rest / 14;
            int k = ks * 32 + ((lane >> 4) * 8) + j;
            int n = nt * 16 + (lane & 15);
            float v = (k < 384) ? W[(size_t)k * 64 + n] : root[(size_t)(k - 384) * 64 + n];
            Bfrag[t] = f2bf(v);
        }
    }
}

// ---- scan over ghist[NG] (bucket-major): per-block inclusive + block sums ----
__global__ void scanA_k(const int* __restrict__ v, int* __restrict__ incl,
                        int* __restrict__ blocksum, int n) {
    __shared__ int s[SB];
    int t = threadIdx.x, i = blockIdx.x * SB + t;
    s[t] = (i < n) ? v[i] : 0;
    __syncthreads();
    for (int off = 1; off < SB; off <<= 1) {
        int u = (t >= off) ? s[t - off] : 0;
        __syncthreads();
        s[t] += u;
        __syncthreads();
    }
    if (i < n) incl[i] = s[t];
    if (t == SB - 1) blocksum[blockIdx.x] = s[t];
}

__global__ void scanB_k(const int* __restrict__ blocksum, int* __restrict__ blockoff, int nb) {
    __shared__ int s[1024];
    int t = threadIdx.x;
    s[t] = (t < nb) ? blocksum[t] : 0;
    __syncthreads();
    for (int off = 1; off < 1024; off <<= 1) {
        int u = (t >= off) ? s[t - off] : 0;
        __syncthreads();
        s[t] += u;
        __syncthreads();
    }
    if (t < nb) blockoff[t] = s[t];
}

// pass 1b: scatter edges into bucket-grouped kv = (src<<9)|(seg&511);
// cursors computed inline from scan outputs (scanC2 deleted).
__global__ __launch_bounds__(256) void scatter1_k(const int* __restrict__ srcs,
                                                  const int* __restrict__ dsts,
                                                  const int* __restrict__ et,
                                                  const int* __restrict__ incl,
                                                  const int* __restrict__ blockoff,
                                                  const int* __restrict__ ghist,
                                                  unsigned int* __restrict__ kv) {
    __shared__ int cur[NBUK];
    int tid = threadIdx.x, blk = blockIdx.x;
    for (int i = tid; i < NBUK; i += 256) {
        int m = i * NBLK1 + blk;
        cur[i] = excl_at(incl, blockoff, ghist, m);
    }
    __syncthreads();
    int base = blk * EPB;
#pragma unroll 5
    for (int i = 0; i < EPB / 256; ++i) {
        int e = base + i * 256 + tid;
        int seg = dsts[e] * NR + et[e];
        int pos = atomicAdd(&cur[seg >> BUKSH], 1);
        kv[pos] = ((unsigned int)srcs[e] << BUKSH) | ((unsigned int)seg & 511u);
    }
}

// pass 2: one block per 512-segment bucket; kv slice cached in LDS (global
// fallback if bucket > KVL_CAP); LDS histogram -> rowstart + pay (ushort src).
__global__ __launch_bounds__(256) void bucket2_k(const unsigned int* __restrict__ kv,
                                                 const int* __restrict__ incl,
                                                 const int* __restrict__ blockoff,
                                                 const int* __restrict__ ghist,
                                                 int* __restrict__ rowstart,
                                                 unsigned short* __restrict__ pay) {
    __shared__ int h[512];
    __shared__ int part[256];
    __shared__ unsigned int kvl[KVL_CAP];
    __shared__ int sbase, send;
    int tid = threadIdx.x, b = blockIdx.x;
    if (tid == 0) {
        sbase = excl_at(incl, blockoff, ghist, b * NBLK1);
        send = (b + 1 < NBUK) ? excl_at(incl, blockoff, ghist, (b + 1) * NBLK1) : NE;
    }
    for (int i = tid; i < 512; i += 256) h[i] = 0;
    __syncthreads();
    int base = sbase, end = send;
    int cnt = end - base;
    bool inlds = (cnt <= KVL_CAP);
    if (inlds) {
        for (int k = tid; k < cnt; k += 256) kvl[k] = kv[base + k];
    }
    __syncthreads();
    for (int k = tid; k < cnt; k += 256) {
        unsigned int v = inlds ? kvl[k] : kv[base + k];
        atomicAdd(&h[v & 511u], 1);
    }
    __syncthreads();
    int c0 = h[2 * tid], c1 = h[2 * tid + 1];
    part[tid] = c0 + c1;
    __syncthreads();
    for (int off = 1; off < 256; off <<= 1) {
        int u = (tid >= off) ? part[tid - off] : 0;
        __syncthreads();
        part[tid] += u;
        __syncthreads();
    }
    int pbase = (tid > 0) ? part[tid - 1] : 0;   // exclusive across thread groups
    __syncthreads();
    int e0 = pbase, e1 = pbase + c0;
    h[2 * tid] = e0; h[2 * tid + 1] = e1;
    int segb = b << BUKSH;
    if (segb + 2 * tid     < NSEG) rowstart[segb + 2 * tid]     = base + e0;
    if (segb + 2 * tid + 1 < NSEG) rowstart[segb + 2 * tid + 1] = base + e1;
    if (b == 0 && tid == 0) rowstart[NSEG] = NE;
    __syncthreads();
    for (int k = tid; k < cnt; k += 256) {
        unsigned int v = inlds ? kvl[k] : kv[base + k];
        int pos = base + atomicAdd(&h[v & 511u], 1);
        pay[pos] = (unsigned short)(v >> BUKSH);
    }
}

// EIGHT segments per wave (round-21/23 exact): lane group g=lane>>3 owns segment
// 8*wv+g; q=lane&7 owns channel octet (uint4 gather; 8 lanes = 128B row).
__global__ __launch_bounds__(256) void agg13_k(const unsigned short* __restrict__ xh,
                                               const int* __restrict__ rowstart,
                                               const unsigned short* __restrict__ pay,
                                               unsigned short* __restrict__ Amain) {
    int wv = (blockIdx.x * blockDim.x + threadIdx.x) >> 6;   // 0..37499 (grid exact)
    int lane = threadIdx.x & 63;
    int g = lane >> 3;
    int q = lane & 7;
    int seg = 8 * wv + g;
    int k0 = rowstart[seg], k1 = rowstart[seg + 1];
    const char* xb = (const char*)xh;
    unsigned int qo = (unsigned int)q << 4;                  // byte offset within row
    float a0 = 0.f, a1 = 0.f, a2 = 0.f, a3 = 0.f;
    float a4 = 0.f, a5 = 0.f, a6 = 0.f, a7 = 0.f;
    int len = k1 - k0;
    int k = k0;
    int k4 = k0 + (len & ~3);
    for (; k < k4; k += 4) {
        unsigned int pv[4];
#pragma unroll
        for (int j = 0; j < 4; ++j) pv[j] = (unsigned int)pay[k + j] << 7;
        uint4 uv[4];
#pragma unroll
        for (int j = 0; j < 4; ++j)
            uv[j] = *(const uint4*)(xb + pv[j] + qo);
#pragma unroll
        for (int j = 0; j < 4; ++j) {
            a0 += __uint_as_float(uv[j].x << 16);
            a1 += __uint_as_float(uv[j].x & 0xFFFF0000u);
            a2 += __uint_as_float(uv[j].y << 16);
            a3 += __uint_as_float(uv[j].y & 0xFFFF0000u);
            a4 += __uint_as_float(uv[j].z << 16);
            a5 += __uint_as_float(uv[j].z & 0xFFFF0000u);
            a6 += __uint_as_float(uv[j].w << 16);
            a7 += __uint_as_float(uv[j].w & 0xFFFF0000u);
        }
    }
    if (k < k1) {                       // masked tail: 1..3 edges
        unsigned int pv[3];
        float mv[3];
#pragma unroll
        for (int j = 0; j < 3; ++j) {
            int kk = k + j;
            bool v = kk < k1;
            mv[j] = v ? 1.0f : 0.0f;
            pv[j] = (unsigned int)pay[v ? kk : k] << 7;
        }
#pragma unroll
        for (int j = 0; j < 3; ++j) {
            uint4 u = *(const uint4*)(xb + pv[j] + qo);
            a0 += __uint_as_float(u.x << 16) * mv[j];
            a1 += __uint_as_float(u.x & 0xFFFF0000u) * mv[j];
            a2 += __uint_as_float(u.y << 16) * mv[j];
            a3 += __uint_as_float(u.y & 0xFFFF0000u) * mv[j];
            a4 += __uint_as_float(u.z << 16) * mv[j];
            a5 += __uint_as_float(u.z & 0xFFFF0000u) * mv[j];
            a6 += __uint_as_float(u.w << 16) * mv[j];
            a7 += __uint_as_float(u.w & 0xFFFF0000u) * mv[j];
        }
    }
    float nrm = (len > 0) ? 1.0f / (float)len : 0.0f;
    uint4 o;
    o.x = (unsigned int)f2bf(a0 * nrm) | ((unsigned int)f2bf(a1 * nrm) << 16);
    o.y = (unsigned int)f2bf(a2 * nrm) | ((unsigned int)f2bf(a3 * nrm) << 16);
    o.z = (unsigned int)f2bf(a4 * nrm) | ((unsigned int)f2bf(a5 * nrm) << 16);
    o.w = (unsigned int)f2bf(a6 * nrm) | ((unsigned int)f2bf(a7 * nrm) << 16);
    *(uint4*)((char*)Amain + (size_t)seg * 128 + qo) = o;
}

// MFMA GEMM: K slots 0-383 from Amain, 384-447 (root term) from xh. (round-18 exact)
__global__ __launch_bounds__(256) void mix4_k(const unsigned short* __restrict__ Amain,
                                              const unsigned short* __restrict__ xh,
                                              const unsigned short* __restrict__ Bfrag,
                                              const float* __restrict__ bias,
                                              float* __restrict__ out) {
    int t = threadIdx.x;
    int lane = t & 63;
    int w = t >> 6;
    int rowb = blockIdx.x * 64 + w * 16;
    int arow = rowb + (lane & 15);
    if (arow >= NN) arow = NN - 1;
    int ko = (lane >> 4) * 8;
    const unsigned short* ap = Amain + (size_t)arow * 384 + ko;
    const unsigned short* xp = xh + (size_t)arow * 64 + ko;
    const short8* bp = (const short8*)Bfrag + lane;
    f32x4 acc0 = {0.f, 0.f, 0.f, 0.f};
    f32x4 acc1 = acc0, acc2 = acc0, acc3 = acc0;
#pragma unroll
    for (int ks = 0; ks < 14; ++ks) {
        short8 a = (ks < 12) ? *(const short8*)(ap + ks * 32)
                             : *(const short8*)(xp + (ks - 12) * 32);
        short8 b0 = bp[(0 * 14 + ks) * 64];
        short8 b1 = bp[(1 * 14 + ks) * 64];
        short8 b2 = bp[(2 * 14 + ks) * 64];
        short8 b3 = bp[(3 * 14 + ks) * 64];
        acc0 = __builtin_amdgcn_mfma_f32_16x16x32_bf16(a, b0, acc0, 0, 0, 0);
        acc1 = __builtin_amdgcn_mfma_f32_16x16x32_bf16(a, b1, acc1, 0, 0, 0);
        acc2 = __builtin_amdgcn_mfma_f32_16x16x32_bf16(a, b2, acc2, 0, 0, 0);
        acc3 = __builtin_amdgcn_mfma_f32_16x16x32_bf16(a, b3, acc3, 0, 0, 0);
    }
    int col = lane & 15;
    int rout = rowb + (lane >> 4) * 4;
    float bv0 = bias[0 * 16 + col];
    float bv1 = bias[1 * 16 + col];
    float bv2 = bias[2 * 16 + col];
    float bv3 = bias[3 * 16 + col];
#pragma unroll
    for (int j = 0; j < 4; ++j) {
        int rr = rout + j;
        if (rr < NN) {
            float* op = out + (size_t)rr * 64;
            op[0 * 16 + col] = acc0[j] + bv0;
            op[1 * 16 + col] = acc1[j] + bv1;
            op[2 * 16 + col] = acc2[j] + bv2;
            op[3 * 16 + col] = acc3[j] + bv3;
        }
    }
}

// ---------- fallback path (small ws) ----------
__global__ void zero_i32_k(int* __restrict__ p, int n) {
    int i = blockIdx.x * blockDim.x + threadIdx.x;
    if (i < n) p[i] = 0;
}

__global__ void count_edges_k(const int* __restrict__ dst, const int* __restrict__ et,
                              int* __restrict__ cnt) {
    int e = blockIdx.x * blockDim.x + threadIdx.x;
    if (e < NE) atomicAdd(&cnt[dst[e] * NR + et[e]], 1);
}

__global__ void make_norm_k(const int* __restrict__ cnt, float* __restrict__ norm, int n) {
    int i = blockIdx.x * blockDim.x + threadIdx.x;
    if (i < n) {
        int c = cnt[i];
        norm[i] = (c > 0) ? 1.0f / (float)c : 0.0f;
    }
}

__global__ void init_out_k(const float* __restrict__ x, const float* __restrict__ root,
                           const float* __restrict__ bias, float* __restrict__ out) {
    int t = blockIdx.x * blockDim.x + threadIdx.x;
    int n = t >> 6;
    int o = t & 63;
    if (n >= NN) return;
    const float* xrow = x + n * D;
    float acc = bias[o];
#pragma unroll
    for (int d = 0; d < D; ++d) acc = fmaf(xrow[d], root[d * D + o], acc);
    out[t] = acc;
}

__global__ void scatter_mv_k(const int* __restrict__ srcs, const int* __restrict__ dsts,
                             const int* __restrict__ et, const float* __restrict__ x,
                             const float* __restrict__ W, const float* __restrict__ norm,
                             float* __restrict__ out) {
    int t = blockIdx.x * blockDim.x + threadIdx.x;
    int e = t >> 6;
    int o = t & 63;
    if (e >= NE) return;
    int s = srcs[e];
    int d2 = dsts[e];
    int r = et[e];
    float nrm = norm[d2 * NR + r];
    const float* xrow = x + s * D;
    const float* Wr = W + r * D * D + o;
    float acc = 0.0f;
#pragma unroll
    for (int d = 0; d < D; ++d) acc = fmaf(xrow[d], Wr[d * D], acc);
    atomicAdd(&out[d2 * D + o], acc * nrm);
}

extern "C" void kernel_launch(void* const* d_in, const int* in_sizes, int n_in,
                              void* d_out, int out_size, void* d_ws, size_t ws_size,
                              hipStream_t stream) {
    const float* x    = (const float*)d_in[0];
    const float* W    = (const float*)d_in[1];
    const float* root = (const float*)d_in[2];
    const float* bias = (const float*)d_in[3];
    const int*   ei   = (const int*)d_in[4];
    const int*   et   = (const int*)d_in[5];
    float* out = (float*)d_out;
    const int* srcs = ei;
    const int* dsts = ei + NE;

    // workspace layout (~57 MB)
    char* ws = (char*)d_ws;
    size_t off = 0;
    int*   rowstart = (int*)(ws + off); off += (size_t)(NSEG + 1) * 4;
    off = (off + 255) & ~(size_t)255;
    unsigned short* pay = (unsigned short*)(ws + off); off += (size_t)NE * 2;
    off = (off + 255) & ~(size_t)255;
    unsigned int* kv = (unsigned int*)(ws + off); off += (size_t)NE * 4;
    int*   ghist    = (int*)(ws + off); off += (size_t)NG * 4;
    int*   incl     = (int*)(ws + off); off += (size_t)NG * 4;
    int*   blocksum = (int*)(ws + off); off += (size_t)SNB1 * 4;
    int*   blockoff = (int*)(ws + off); off += (size_t)SNB1 * 4;
    off = (off + 255) & ~(size_t)255;
    unsigned short* Bfrag = (unsigned short*)(ws + off); off += (size_t)BFRAG_N * 2;
    off = (off + 255) & ~(size_t)255;
    unsigned short* xh = (unsigned short*)(ws + off); off += (size_t)NN * D * 2;
    off = (off + 255) & ~(size_t)255;
    unsigned short* Amain = (unsigned short*)(ws + off); off += (size_t)NN * 384 * 2;
    bool big = ws_size >= off;

    if (big) {
        prep_hist_k<<<NBLK1 + PREPB, 256, 0, stream>>>(x, W, root, dsts, et, ghist, xh, Bfrag);
        scanA_k<<<SNB1, SB, 0, stream>>>(ghist, incl, blocksum, NG);
        scanB_k<<<1, 1024, 0, stream>>>(blocksum, blockoff, SNB1);
        scatter1_k<<<NBLK1, 256, 0, stream>>>(srcs, dsts, et, incl, blockoff, ghist, kv);
        bucket2_k<<<NBUK, 256, 0, stream>>>(kv, incl, blockoff, ghist, rowstart, pay);
        int aggwaves = NSEG / 8;                      // 37500
        agg13_k<<<((size_t)aggwaves * 64 + 255) / 256, 256, 0, stream>>>(xh, rowstart, pay, Amain);
        mix4_k<<<(NN + 63) / 64, 256, 0, stream>>>(Amain, xh, Bfrag, bias, out);
    } else {
        int* cnt2  = (int*)(ws);
        float* norm = (float*)(ws + (size_t)NSEG * 4);
        zero_i32_k<<<(NSEG + 255) / 256, 256, 0, stream>>>(cnt2, NSEG);
        count_edges_k<<<(NE + 255) / 256, 256, 0, stream>>>(dsts, et, cnt2);
        make_norm_k<<<(NSEG + 255) / 256, 256, 0, stream>>>(cnt2, norm, NSEG);
        init_out_k<<<((size_t)NN * 64 + 255) / 256, 256, 0, stream>>>(x, root, bias, out);
        scatter_mv_k<<<((size_t)NE * 64 + 255) / 256, 256, 0, stream>>>(srcs, dsts, et, x, W, norm, out);
    }
}